// Round 5
// baseline (163.649 us; speedup 1.0000x reference)
//
#include <hip/hip_runtime.h>
#include <hip/hip_bf16.h>

// SimpleDIN fused kernel v5 — no beh in LDS (pool from A-frag registers),
// LDS ~13.5 KB -> 8 blocks/CU (32 waves), launch_bounds(256,8).
//
// Algebra: feats=[beh,tgt,beh*tgt,beh-tgt] (K=256) collapses:
//   feats @ W1 == beh @ W_eff + bias_eff   (K=64)
//   W_eff[d,j]  = W1[d,j] + tgt[d]*W1[128+d,j] + W1[192+d,j]
//   bias_eff[j] = b1[j] + sum_d tgt[d]*(W1[64+d,j] - W1[192+d,j])
// att_b2 cancels in softmax.

#define B_SZ  4096
#define S_SZ  200
#define D_SZ  64
#define H_SZ  80

typedef __attribute__((ext_vector_type(8))) short          bf16x8;
typedef __attribute__((ext_vector_type(8))) unsigned short u16x8;
typedef __attribute__((ext_vector_type(4))) float          f32x4;

struct __align__(16) Lds {
    unsigned short wefft[H_SZ * 64];   // 10240 B, swizzled bf16 [j][d]
    float w2l[H_SZ];                   // 320
    float bias_eff[H_SZ];              // 320
    float scores[S_SZ];                // 800
    float x[2 * D_SZ];                 // 512
    float h1[64];                      // 256
    float pp[4 * 64];                  // 1024 (pool partials / MLP partials x2? no: 256 fl)
    float red[8];                      // 32
};                                      // ~13.6 KB -> wave-slot-bound (8 blocks)

__device__ __forceinline__ int swz_gran(int row, int g) {
    return row * 64 + ((g ^ (row & 7)) << 3);      // u16 index of 16B granule
}
__device__ __forceinline__ int swz_elem(int row, int col) {
    return row * 64 + (((col >> 3) ^ (row & 7)) << 3) + (col & 7);
}
__device__ __forceinline__ float bits2f(unsigned int u) {
    union { unsigned int u; float f; } v; v.u = u; return v.f;
}
__device__ __forceinline__ float bfelem(bf16x8 v, int e) {
    return bits2f(((unsigned int)(unsigned short)v[e]) << 16);
}

extern "C" __global__ __launch_bounds__(256, 8)
void din_fused(const int* __restrict__ user_ids,
               const int* __restrict__ item_ids,
               const int* __restrict__ seq,
               const float* __restrict__ user_table,
               const float* __restrict__ item_table,
               const float* __restrict__ att_w1,
               const float* __restrict__ att_b1,
               const float* __restrict__ att_w2,
               const float* __restrict__ pred_w1,
               const float* __restrict__ pred_b1,
               const float* __restrict__ pred_w2,
               const float* __restrict__ pred_b2,
               const float* __restrict__ pred_w3,
               const float* __restrict__ pred_b3,
               float* __restrict__ out)
{
    __shared__ Lds L;
    const int b = blockIdx.x;
    const int t = threadIdx.x;

    const int wv = t >> 6;                  // wave 0..3
    const int l  = t & 63;
    const int lr = l & 15;                  // M-row / N-col within tile
    const int ks = l >> 4;                  // k-slot 0..3

    // ---- phase 0: small per-block loads (no barrier needed until MFMA) ----
    const int uid = user_ids[b];
    const int iid = item_ids[b];
    if (t < 64) {
        L.x[t] = user_table[(size_t)uid * D_SZ + t];
    } else if (t < 64 + H_SZ) {
        L.w2l[t - 64] = att_w2[t - 64];
    }

    // ---- phase 1: gather A-frags global -> registers -> bf16 ----
    // thread (wv,lr,ks), tile i: mt = wv+4i, row seq[mt*16+lr];
    // A0 covers d=8ks..8ks+7, A1 covers d=32+8ks..32+8ks+7
    bf16x8 A0[4], A1[4];
    #pragma unroll
    for (int i = 0; i < 4; ++i) {
        const int mt = wv + i * 4;
        const int srow = mt * 16 + lr;
        const bool v = (mt < 13) && (srow < S_SZ);
        union { u16x8 u; bf16x8 bf; __hip_bfloat162 h2[4]; } c0, c1;
        if (v) {
            const int row = seq[b * S_SZ + srow];
            const float4* src = reinterpret_cast<const float4*>(
                item_table + (size_t)row * D_SZ);
            const float4 q0 = src[2 * ks];
            const float4 q1 = src[2 * ks + 1];
            const float4 q2 = src[8 + 2 * ks];
            const float4 q3 = src[8 + 2 * ks + 1];
            c0.h2[0] = __float22bfloat162_rn(float2{q0.x, q0.y});
            c0.h2[1] = __float22bfloat162_rn(float2{q0.z, q0.w});
            c0.h2[2] = __float22bfloat162_rn(float2{q1.x, q1.y});
            c0.h2[3] = __float22bfloat162_rn(float2{q1.z, q1.w});
            c1.h2[0] = __float22bfloat162_rn(float2{q2.x, q2.y});
            c1.h2[1] = __float22bfloat162_rn(float2{q2.z, q2.w});
            c1.h2[2] = __float22bfloat162_rn(float2{q3.x, q3.y});
            c1.h2[3] = __float22bfloat162_rn(float2{q3.z, q3.w});
        } else {
            c0.u = (u16x8)0;
            c1.u = (u16x8)0;
        }
        A0[i] = c0.bf;
        A1[i] = c1.bf;
    }

    // ---- phase 2: W_eff^T (bf16, swizzled) + bias_eff ----
    // tgt read straight from global (same addr across j-lanes -> L1 bcast)
    const float* tgtp = item_table + (size_t)iid * D_SZ;
    for (int i = t; i < 32 * H_SZ; i += 256) {
        const int dp = i / H_SZ;
        const int j  = i - dp * H_SZ;
        const int d  = dp * 2;
        const float2 tg = *reinterpret_cast<const float2*>(tgtp + d);
        const float w0 = att_w1[d * H_SZ + j]
                       + tg.x * att_w1[(128 + d) * H_SZ + j]
                       + att_w1[(192 + d) * H_SZ + j];
        const float w1 = att_w1[(d + 1) * H_SZ + j]
                       + tg.y * att_w1[(129 + d) * H_SZ + j]
                       + att_w1[(193 + d) * H_SZ + j];
        const __hip_bfloat162 hp = __float22bfloat162_rn(float2{w0, w1});
        *reinterpret_cast<__hip_bfloat162*>(&L.wefft[swz_elem(j, d)]) = hp;
    }
    if (t < 2 * H_SZ) {                     // 2 threads per j, 32 d each
        const int j = t >> 1;
        const int h = t & 1;
        float acc = h ? 0.f : att_b1[j];
        const int d0 = h * 32;
        #pragma unroll 4
        for (int d = d0; d < d0 + 32; ++d)
            acc += tgtp[d] * (att_w1[(64 + d) * H_SZ + j]
                            - att_w1[(192 + d) * H_SZ + j]);
        acc += __shfl_xor(acc, 1);
        if (h == 0) L.bias_eff[j] = acc;
    }
    __syncthreads();    // wefft + bias + w2l + x(user) ready

    // ---- phase 3: MFMA  C[s,j] = beh @ W_eff; logits = relu(C+b)·w2 ----
    #pragma unroll
    for (int i = 0; i < 4; ++i) {
        const int mt = wv + i * 4;
        if (mt >= 13) break;
        f32x4 acc[5];
        #pragma unroll
        for (int nt = 0; nt < 5; ++nt)
            acc[nt] = (f32x4){0.f, 0.f, 0.f, 0.f};
        #pragma unroll
        for (int nt = 0; nt < 5; ++nt) {
            const int j = nt * 16 + lr;
            const bf16x8 b0 = *reinterpret_cast<const bf16x8*>(
                &L.wefft[swz_gran(j, ks)]);
            const bf16x8 b1 = *reinterpret_cast<const bf16x8*>(
                &L.wefft[swz_gran(j, 4 + ks)]);
            acc[nt] = __builtin_amdgcn_mfma_f32_16x16x32_bf16(
                A0[i], b0, acc[nt], 0, 0, 0);
            acc[nt] = __builtin_amdgcn_mfma_f32_16x16x32_bf16(
                A1[i], b1, acc[nt], 0, 0, 0);
        }
        #pragma unroll
        for (int r = 0; r < 4; ++r) {
            const int s = mt * 16 + ks * 4 + r;
            float p = 0.f;
            #pragma unroll
            for (int nt = 0; nt < 5; ++nt) {
                const int j = nt * 16 + lr;
                const float h = acc[nt][r] + L.bias_eff[j];
                p += fmaxf(h, 0.f) * L.w2l[j];
            }
            p += __shfl_xor(p, 1);
            p += __shfl_xor(p, 2);
            p += __shfl_xor(p, 4);
            p += __shfl_xor(p, 8);
            if (lr == 0 && s < S_SZ) L.scores[s] = p;
        }
    }
    __syncthreads();

    // ---- phase 4: softmax over 200 logits ----
    const float raw = (t < S_SZ) ? L.scores[t] : -1e30f;
    float m = raw;
    #pragma unroll
    for (int off = 32; off; off >>= 1) m = fmaxf(m, __shfl_xor(m, off));
    if ((t & 63) == 0) L.red[t >> 6] = m;
    __syncthreads();
    m = fmaxf(fmaxf(L.red[0], L.red[1]), fmaxf(L.red[2], L.red[3]));
    const float e = (t < S_SZ) ? __expf(raw - m) : 0.f;
    if (t < S_SZ) L.scores[t] = e;
    float ssum = e;
    #pragma unroll
    for (int off = 32; off; off >>= 1) ssum += __shfl_xor(ssum, off);
    if ((t & 63) == 0) L.red[4 + (t >> 6)] = ssum;
    __syncthreads();
    const float inv = 1.f / (L.red[4] + L.red[5] + L.red[6] + L.red[7]);

    // ---- phase 5: pooled from A-frag registers ----
    // pl[e]: d=8ks+e, ph[e]: d=32+8ks+e; reduce over 16 lr lanes (butterfly)
    {
        float pl[8], ph[8];
        #pragma unroll
        for (int e = 0; e < 8; ++e) { pl[e] = 0.f; ph[e] = 0.f; }
        #pragma unroll
        for (int i = 0; i < 4; ++i) {
            const int mt = wv + i * 4;
            if (mt >= 13) break;
            const int srow = mt * 16 + lr;
            const float w = (srow < S_SZ) ? L.scores[srow] : 0.f;
            #pragma unroll
            for (int e = 0; e < 8; ++e) {
                pl[e] = fmaf(w, bfelem(A0[i], e), pl[e]);
                ph[e] = fmaf(w, bfelem(A1[i], e), ph[e]);
            }
        }
        #pragma unroll
        for (int msk = 1; msk < 16; msk <<= 1) {
            #pragma unroll
            for (int e = 0; e < 8; ++e) {
                pl[e] += __shfl_xor(pl[e], msk);
                ph[e] += __shfl_xor(ph[e], msk);
            }
        }
        if (lr == 0) {
            #pragma unroll
            for (int e = 0; e < 8; ++e) {
                L.pp[wv * 64 + 8 * ks + e]      = pl[e];
                L.pp[wv * 64 + 32 + 8 * ks + e] = ph[e];
            }
        }
    }
    __syncthreads();
    if (t < D_SZ) {
        L.x[D_SZ + t] = (L.pp[t] + L.pp[64 + t]
                       + L.pp[128 + t] + L.pp[192 + t]) * inv;
    }
    __syncthreads();

    // ---- phase 6: prediction MLP 128 -> 64 -> 32 -> 1 (all threads) ----
    {
        const int j  = t & 63;
        const int k0 = (t >> 6) * 32;
        float acc = 0.f;
        for (int k = k0; k < k0 + 32; ++k)
            acc = fmaf(L.x[k], pred_w1[k * 64 + j], acc);
        L.pp[(t >> 6) * 64 + j] = acc;
    }
    __syncthreads();
    if (t < 64) {
        const float a = pred_b1[t] + L.pp[t] + L.pp[64 + t]
                      + L.pp[128 + t] + L.pp[192 + t];
        L.h1[t] = fmaxf(a, 0.f);
    }
    __syncthreads();
    {
        const int j  = t & 31;
        const int k0 = (t >> 5) * 8;
        float acc = 0.f;
        #pragma unroll
        for (int k = k0; k < k0 + 8; ++k)
            acc = fmaf(L.h1[k], pred_w2[k * 32 + j], acc);
        L.pp[(t >> 5) * 32 + j] = acc;
    }
    __syncthreads();
    if (t < 32) {
        float a = pred_b2[t];
        #pragma unroll
        for (int q = 0; q < 8; ++q) a += L.pp[q * 32 + t];
        float p = fmaxf(a, 0.f) * pred_w3[t];
        p += __shfl_xor(p, 1);
        p += __shfl_xor(p, 2);
        p += __shfl_xor(p, 4);
        p += __shfl_xor(p, 8);
        p += __shfl_xor(p, 16);
        if (t == 0) {
            const float z = p + pred_b3[0];
            out[b] = 1.f / (1.f + __expf(-z));
        }
    }
}

extern "C" void kernel_launch(void* const* d_in, const int* in_sizes, int n_in,
                              void* d_out, int out_size, void* d_ws, size_t ws_size,
                              hipStream_t stream)
{
    const int*   user_ids   = (const int*)  d_in[0];
    const int*   item_ids   = (const int*)  d_in[1];
    const int*   seq        = (const int*)  d_in[2];
    const float* user_table = (const float*)d_in[3];
    const float* item_table = (const float*)d_in[4];
    const float* att_w1     = (const float*)d_in[5];
    const float* att_b1     = (const float*)d_in[6];
    const float* att_w2     = (const float*)d_in[7];
    // d_in[8] = att_b2: cancels in softmax, unused
    const float* pred_w1    = (const float*)d_in[9];
    const float* pred_b1    = (const float*)d_in[10];
    const float* pred_w2    = (const float*)d_in[11];
    const float* pred_b2    = (const float*)d_in[12];
    const float* pred_w3    = (const float*)d_in[13];
    const float* pred_b3    = (const float*)d_in[14];
    float* out = (float*)d_out;

    din_fused<<<B_SZ, 256, 0, stream>>>(user_ids, item_ids, seq,
                                        user_table, item_table,
                                        att_w1, att_b1, att_w2,
                                        pred_w1, pred_b1, pred_w2, pred_b2,
                                        pred_w3, pred_b3, out);
}

// Round 6
// 122.930 us; speedup vs baseline: 1.3312x; 1.3312x over previous
//
#include <hip/hip_runtime.h>
#include <hip/hip_bf16.h>

// SimpleDIN fused kernel v6 — v5 structure (no beh in LDS, pool from A-frag
// registers, 13.8 KB LDS) with a sane register budget: launch_bounds(256,5)
// -> ~102 VGPR cap, no scratch spill, ~20 waves/CU.
//
// Algebra: feats=[beh,tgt,beh*tgt,beh-tgt] (K=256) collapses:
//   feats @ W1 == beh @ W_eff + bias_eff   (K=64)
//   W_eff[d,j]  = W1[d,j] + tgt[d]*W1[128+d,j] + W1[192+d,j]
//   bias_eff[j] = b1[j] + sum_d tgt[d]*(W1[64+d,j] - W1[192+d,j])
// att_b2 cancels in softmax.

#define B_SZ  4096
#define S_SZ  200
#define D_SZ  64
#define H_SZ  80

typedef __attribute__((ext_vector_type(8))) short          bf16x8;
typedef __attribute__((ext_vector_type(8))) unsigned short u16x8;
typedef __attribute__((ext_vector_type(4))) float          f32x4;

struct __align__(16) Lds {
    unsigned short wefft[H_SZ * 64];   // 10240 B, swizzled bf16 [j][d]
    float w2l[H_SZ];
    float bias_eff[H_SZ];
    float scores[S_SZ];
    float x[2 * D_SZ];
    float h1[64];
    float pp[4 * 64];
    float red[8];
};                                      // ~13.8 KB

__device__ __forceinline__ int swz_gran(int row, int g) {
    return row * 64 + ((g ^ (row & 7)) << 3);      // u16 index of 16B granule
}
__device__ __forceinline__ int swz_elem(int row, int col) {
    return row * 64 + (((col >> 3) ^ (row & 7)) << 3) + (col & 7);
}
__device__ __forceinline__ float bits2f(unsigned int u) {
    union { unsigned int u; float f; } v; v.u = u; return v.f;
}
__device__ __forceinline__ float bfelem(bf16x8 v, int e) {
    return bits2f(((unsigned int)(unsigned short)v[e]) << 16);
}

extern "C" __global__ __launch_bounds__(256, 5)
void din_fused(const int* __restrict__ user_ids,
               const int* __restrict__ item_ids,
               const int* __restrict__ seq,
               const float* __restrict__ user_table,
               const float* __restrict__ item_table,
               const float* __restrict__ att_w1,
               const float* __restrict__ att_b1,
               const float* __restrict__ att_w2,
               const float* __restrict__ pred_w1,
               const float* __restrict__ pred_b1,
               const float* __restrict__ pred_w2,
               const float* __restrict__ pred_b2,
               const float* __restrict__ pred_w3,
               const float* __restrict__ pred_b3,
               float* __restrict__ out)
{
    __shared__ Lds L;
    const int b = blockIdx.x;
    const int t = threadIdx.x;

    const int wv = t >> 6;                  // wave 0..3
    const int l  = t & 63;
    const int lr = l & 15;                  // M-row / N-col within tile
    const int ks = l >> 4;                  // k-slot 0..3

    // ---- phase 0: small per-block loads ----
    const int uid = user_ids[b];
    const int iid = item_ids[b];
    if (t < 64) {
        L.x[t] = user_table[(size_t)uid * D_SZ + t];
    } else if (t < 64 + H_SZ) {
        L.w2l[t - 64] = att_w2[t - 64];
    }

    // ---- phase 1: gather A-frags global -> registers -> bf16 ----
    // prefetch the 4 row ids first (shortens dependent chain), then loads
    int rows_[4];
    #pragma unroll
    for (int i = 0; i < 4; ++i) {
        const int mt = wv + i * 4;
        const int srow = mt * 16 + lr;
        rows_[i] = (mt < 13 && srow < S_SZ) ? seq[b * S_SZ + srow] : -1;
    }
    bf16x8 A0[4], A1[4];
    #pragma unroll
    for (int i = 0; i < 4; ++i) {
        union { u16x8 u; bf16x8 bf; __hip_bfloat162 h2[4]; } c0, c1;
        if (rows_[i] >= 0) {
            const float4* src = reinterpret_cast<const float4*>(
                item_table + (size_t)rows_[i] * D_SZ);
            const float4 q0 = src[2 * ks];
            const float4 q1 = src[2 * ks + 1];
            const float4 q2 = src[8 + 2 * ks];
            const float4 q3 = src[8 + 2 * ks + 1];
            c0.h2[0] = __float22bfloat162_rn(float2{q0.x, q0.y});
            c0.h2[1] = __float22bfloat162_rn(float2{q0.z, q0.w});
            c0.h2[2] = __float22bfloat162_rn(float2{q1.x, q1.y});
            c0.h2[3] = __float22bfloat162_rn(float2{q1.z, q1.w});
            c1.h2[0] = __float22bfloat162_rn(float2{q2.x, q2.y});
            c1.h2[1] = __float22bfloat162_rn(float2{q2.z, q2.w});
            c1.h2[2] = __float22bfloat162_rn(float2{q3.x, q3.y});
            c1.h2[3] = __float22bfloat162_rn(float2{q3.z, q3.w});
        } else {
            c0.u = (u16x8)0;
            c1.u = (u16x8)0;
        }
        A0[i] = c0.bf;
        A1[i] = c1.bf;
    }

    // ---- phase 2: W_eff^T (bf16, swizzled) + bias_eff ----
    const float* tgtp = item_table + (size_t)iid * D_SZ;
    for (int i = t; i < 32 * H_SZ; i += 256) {
        const int dp = i / H_SZ;
        const int j  = i - dp * H_SZ;
        const int d  = dp * 2;
        const float2 tg = *reinterpret_cast<const float2*>(tgtp + d);
        const float w0 = att_w1[d * H_SZ + j]
                       + tg.x * att_w1[(128 + d) * H_SZ + j]
                       + att_w1[(192 + d) * H_SZ + j];
        const float w1 = att_w1[(d + 1) * H_SZ + j]
                       + tg.y * att_w1[(129 + d) * H_SZ + j]
                       + att_w1[(193 + d) * H_SZ + j];
        const __hip_bfloat162 hp = __float22bfloat162_rn(float2{w0, w1});
        *reinterpret_cast<__hip_bfloat162*>(&L.wefft[swz_elem(j, d)]) = hp;
    }
    if (t < 2 * H_SZ) {                     // 2 threads per j, 32 d each
        const int j = t >> 1;
        const int h = t & 1;
        float acc = h ? 0.f : att_b1[j];
        const int d0 = h * 32;
        #pragma unroll 4
        for (int d = d0; d < d0 + 32; ++d)
            acc += tgtp[d] * (att_w1[(64 + d) * H_SZ + j]
                            - att_w1[(192 + d) * H_SZ + j]);
        acc += __shfl_xor(acc, 1);
        if (h == 0) L.bias_eff[j] = acc;
    }
    __syncthreads();    // wefft + bias + w2l + x(user) ready

    // ---- phase 3: MFMA  C[s,j] = beh @ W_eff; logits = relu(C+b)·w2 ----
    #pragma unroll
    for (int i = 0; i < 4; ++i) {
        const int mt = wv + i * 4;
        if (mt >= 13) break;
        f32x4 acc[5];
        #pragma unroll
        for (int nt = 0; nt < 5; ++nt)
            acc[nt] = (f32x4){0.f, 0.f, 0.f, 0.f};
        #pragma unroll
        for (int nt = 0; nt < 5; ++nt) {
            const int j = nt * 16 + lr;
            const bf16x8 b0 = *reinterpret_cast<const bf16x8*>(
                &L.wefft[swz_gran(j, ks)]);
            const bf16x8 b1 = *reinterpret_cast<const bf16x8*>(
                &L.wefft[swz_gran(j, 4 + ks)]);
            acc[nt] = __builtin_amdgcn_mfma_f32_16x16x32_bf16(
                A0[i], b0, acc[nt], 0, 0, 0);
            acc[nt] = __builtin_amdgcn_mfma_f32_16x16x32_bf16(
                A1[i], b1, acc[nt], 0, 0, 0);
        }
        #pragma unroll
        for (int r = 0; r < 4; ++r) {
            const int s = mt * 16 + ks * 4 + r;
            float p = 0.f;
            #pragma unroll
            for (int nt = 0; nt < 5; ++nt) {
                const int j = nt * 16 + lr;
                const float h = acc[nt][r] + L.bias_eff[j];
                p += fmaxf(h, 0.f) * L.w2l[j];
            }
            p += __shfl_xor(p, 1);
            p += __shfl_xor(p, 2);
            p += __shfl_xor(p, 4);
            p += __shfl_xor(p, 8);
            if (lr == 0 && s < S_SZ) L.scores[s] = p;
        }
    }
    __syncthreads();

    // ---- phase 4: softmax over 200 logits ----
    const float raw = (t < S_SZ) ? L.scores[t] : -1e30f;
    float m = raw;
    #pragma unroll
    for (int off = 32; off; off >>= 1) m = fmaxf(m, __shfl_xor(m, off));
    if ((t & 63) == 0) L.red[t >> 6] = m;
    __syncthreads();
    m = fmaxf(fmaxf(L.red[0], L.red[1]), fmaxf(L.red[2], L.red[3]));
    const float e = (t < S_SZ) ? __expf(raw - m) : 0.f;
    if (t < S_SZ) L.scores[t] = e;
    float ssum = e;
    #pragma unroll
    for (int off = 32; off; off >>= 1) ssum += __shfl_xor(ssum, off);
    if ((t & 63) == 0) L.red[4 + (t >> 6)] = ssum;
    __syncthreads();
    const float inv = 1.f / (L.red[4] + L.red[5] + L.red[6] + L.red[7]);

    // ---- phase 5: pooled from A-frag registers ----
    {
        float pl[8], ph[8];
        #pragma unroll
        for (int e = 0; e < 8; ++e) { pl[e] = 0.f; ph[e] = 0.f; }
        #pragma unroll
        for (int i = 0; i < 4; ++i) {
            const int mt = wv + i * 4;
            if (mt >= 13) break;
            const int srow = mt * 16 + lr;
            const float w = (srow < S_SZ) ? L.scores[srow] : 0.f;
            #pragma unroll
            for (int e = 0; e < 8; ++e) {
                pl[e] = fmaf(w, bfelem(A0[i], e), pl[e]);
                ph[e] = fmaf(w, bfelem(A1[i], e), ph[e]);
            }
        }
        #pragma unroll
        for (int msk = 1; msk < 16; msk <<= 1) {
            #pragma unroll
            for (int e = 0; e < 8; ++e) {
                pl[e] += __shfl_xor(pl[e], msk);
                ph[e] += __shfl_xor(ph[e], msk);
            }
        }
        if (lr == 0) {
            #pragma unroll
            for (int e = 0; e < 8; ++e) {
                L.pp[wv * 64 + 8 * ks + e]      = pl[e];
                L.pp[wv * 64 + 32 + 8 * ks + e] = ph[e];
            }
        }
    }
    __syncthreads();
    if (t < D_SZ) {
        L.x[D_SZ + t] = (L.pp[t] + L.pp[64 + t]
                       + L.pp[128 + t] + L.pp[192 + t]) * inv;
    }
    __syncthreads();

    // ---- phase 6: prediction MLP 128 -> 64 -> 32 -> 1 (all threads) ----
    {
        const int j  = t & 63;
        const int k0 = (t >> 6) * 32;
        float acc = 0.f;
        for (int k = k0; k < k0 + 32; ++k)
            acc = fmaf(L.x[k], pred_w1[k * 64 + j], acc);
        L.pp[(t >> 6) * 64 + j] = acc;
    }
    __syncthreads();
    if (t < 64) {
        const float a = pred_b1[t] + L.pp[t] + L.pp[64 + t]
                      + L.pp[128 + t] + L.pp[192 + t];
        L.h1[t] = fmaxf(a, 0.f);
    }
    __syncthreads();
    {
        const int j  = t & 31;
        const int k0 = (t >> 5) * 8;
        float acc = 0.f;
        #pragma unroll
        for (int k = k0; k < k0 + 8; ++k)
            acc = fmaf(L.h1[k], pred_w2[k * 32 + j], acc);
        L.pp[(t >> 5) * 32 + j] = acc;
    }
    __syncthreads();
    if (t < 32) {
        float a = pred_b2[t];
        #pragma unroll
        for (int q = 0; q < 8; ++q) a += L.pp[q * 32 + t];
        float p = fmaxf(a, 0.f) * pred_w3[t];
        p += __shfl_xor(p, 1);
        p += __shfl_xor(p, 2);
        p += __shfl_xor(p, 4);
        p += __shfl_xor(p, 8);
        p += __shfl_xor(p, 16);
        if (t == 0) {
            const float z = p + pred_b3[0];
            out[b] = 1.f / (1.f + __expf(-z));
        }
    }
}

extern "C" void kernel_launch(void* const* d_in, const int* in_sizes, int n_in,
                              void* d_out, int out_size, void* d_ws, size_t ws_size,
                              hipStream_t stream)
{
    const int*   user_ids   = (const int*)  d_in[0];
    const int*   item_ids   = (const int*)  d_in[1];
    const int*   seq        = (const int*)  d_in[2];
    const float* user_table = (const float*)d_in[3];
    const float* item_table = (const float*)d_in[4];
    const float* att_w1     = (const float*)d_in[5];
    const float* att_b1     = (const float*)d_in[6];
    const float* att_w2     = (const float*)d_in[7];
    // d_in[8] = att_b2: cancels in softmax, unused
    const float* pred_w1    = (const float*)d_in[9];
    const float* pred_b1    = (const float*)d_in[10];
    const float* pred_w2    = (const float*)d_in[11];
    const float* pred_b2    = (const float*)d_in[12];
    const float* pred_w3    = (const float*)d_in[13];
    const float* pred_b3    = (const float*)d_in[14];
    float* out = (float*)d_out;

    din_fused<<<B_SZ, 256, 0, stream>>>(user_ids, item_ids, seq,
                                        user_table, item_table,
                                        att_w1, att_b1, att_w2,
                                        pred_w1, pred_b1, pred_w2, pred_b2,
                                        pred_w3, pred_b3, out);
}

// Round 7
// 100.935 us; speedup vs baseline: 1.6213x; 1.2179x over previous
//
#include <hip/hip_runtime.h>
#include <hip/hip_bf16.h>

// SimpleDIN fused kernel v7 — small LDS (14 KB), NO long register live
// ranges: A-tiles loaded fresh from global inside the MFMA loop, pooling
// re-reads item rows in f32 (L3-hot). Target: high occupancy, zero scratch.
//
// Algebra: feats=[beh,tgt,beh*tgt,beh-tgt] (K=256) collapses:
//   feats @ W1 == beh @ W_eff + bias_eff   (K=64)
//   W_eff[d,j]  = W1[d,j] + tgt[d]*W1[128+d,j] + W1[192+d,j]
//   bias_eff[j] = b1[j] + sum_d tgt[d]*(W1[64+d,j] - W1[192+d,j])
// att_b2 cancels in softmax.

#define B_SZ  4096
#define S_SZ  200
#define D_SZ  64
#define H_SZ  80

typedef __attribute__((ext_vector_type(8))) short          bf16x8;
typedef __attribute__((ext_vector_type(8))) unsigned short u16x8;
typedef __attribute__((ext_vector_type(4))) float          f32x4;

struct __align__(16) Lds {
    unsigned short wefft[H_SZ * 64];   // 10240 B, swizzled bf16 [j][d]
    float w2l[H_SZ];
    float bias_eff[H_SZ];
    float scores[S_SZ];
    float x[2 * D_SZ];
    float h1[64];
    float pp[4 * 64];
    float red[8];
};                                      // ~13.8 KB

__device__ __forceinline__ int swz_gran(int row, int g) {
    return row * 64 + ((g ^ (row & 7)) << 3);      // u16 index of 16B granule
}
__device__ __forceinline__ int swz_elem(int row, int col) {
    return row * 64 + (((col >> 3) ^ (row & 7)) << 3) + (col & 7);
}

extern "C" __global__ __launch_bounds__(256, 6)
void din_fused(const int* __restrict__ user_ids,
               const int* __restrict__ item_ids,
               const int* __restrict__ seq,
               const float* __restrict__ user_table,
               const float* __restrict__ item_table,
               const float* __restrict__ att_w1,
               const float* __restrict__ att_b1,
               const float* __restrict__ att_w2,
               const float* __restrict__ pred_w1,
               const float* __restrict__ pred_b1,
               const float* __restrict__ pred_w2,
               const float* __restrict__ pred_b2,
               const float* __restrict__ pred_w3,
               const float* __restrict__ pred_b3,
               float* __restrict__ out)
{
    __shared__ Lds L;
    const int b = blockIdx.x;
    const int t = threadIdx.x;

    const int wv = t >> 6;                  // wave 0..3
    const int l  = t & 63;
    const int lr = l & 15;                  // M-row / N-col within tile
    const int ks = l >> 4;                  // k-slot 0..3

    // ---- phase 0: small per-block loads ----
    const int uid = user_ids[b];
    const int iid = item_ids[b];
    if (t < 64) {
        L.x[t] = user_table[(size_t)uid * D_SZ + t];
    } else if (t < 64 + H_SZ) {
        L.w2l[t - 64] = att_w2[t - 64];
    }

    // row ids for this thread's 4 M-tiles (4 ints live across phases; cheap)
    int rows_[4];
    #pragma unroll
    for (int i = 0; i < 4; ++i) {
        const int mt = wv + i * 4;
        const int srow = mt * 16 + lr;
        rows_[i] = (mt < 13 && srow < S_SZ) ? seq[b * S_SZ + srow] : -1;
    }

    // ---- phase 2: W_eff^T (bf16, swizzled) + bias_eff ----
    const float* tgtp = item_table + (size_t)iid * D_SZ;
    for (int i = t; i < 32 * H_SZ; i += 256) {
        const int dp = i / H_SZ;
        const int j  = i - dp * H_SZ;
        const int d  = dp * 2;
        const float2 tg = *reinterpret_cast<const float2*>(tgtp + d);
        const float w0 = att_w1[d * H_SZ + j]
                       + tg.x * att_w1[(128 + d) * H_SZ + j]
                       + att_w1[(192 + d) * H_SZ + j];
        const float w1 = att_w1[(d + 1) * H_SZ + j]
                       + tg.y * att_w1[(129 + d) * H_SZ + j]
                       + att_w1[(193 + d) * H_SZ + j];
        const __hip_bfloat162 hp = __float22bfloat162_rn(float2{w0, w1});
        *reinterpret_cast<__hip_bfloat162*>(&L.wefft[swz_elem(j, d)]) = hp;
    }
    if (t < 2 * H_SZ) {                     // 2 threads per j, 32 d each
        const int j = t >> 1;
        const int h = t & 1;
        float acc = h ? 0.f : att_b1[j];
        const int d0 = h * 32;
        #pragma unroll 4
        for (int d = d0; d < d0 + 32; ++d)
            acc += tgtp[d] * (att_w1[(64 + d) * H_SZ + j]
                            - att_w1[(192 + d) * H_SZ + j]);
        acc += __shfl_xor(acc, 1);
        if (h == 0) L.bias_eff[j] = acc;
    }
    __syncthreads();    // wefft + bias + w2l + x(user) ready

    // ---- phase 3: MFMA  C[s,j] = beh @ W_eff; logits = relu(C+b)·w2 ----
    // A-tile loaded fresh per iteration: load -> cvt -> MFMA -> discard
    #pragma unroll
    for (int i = 0; i < 4; ++i) {
        const int mt = wv + i * 4;
        const int r_ = rows_[i];
        union { u16x8 u; bf16x8 bf; __hip_bfloat162 h2[4]; } c0, c1;
        if (r_ >= 0) {
            const float4* src = reinterpret_cast<const float4*>(
                item_table + (size_t)r_ * D_SZ);
            const float4 q0 = src[2 * ks];
            const float4 q1 = src[2 * ks + 1];
            const float4 q2 = src[8 + 2 * ks];
            const float4 q3 = src[8 + 2 * ks + 1];
            c0.h2[0] = __float22bfloat162_rn(float2{q0.x, q0.y});
            c0.h2[1] = __float22bfloat162_rn(float2{q0.z, q0.w});
            c0.h2[2] = __float22bfloat162_rn(float2{q1.x, q1.y});
            c0.h2[3] = __float22bfloat162_rn(float2{q1.z, q1.w});
            c1.h2[0] = __float22bfloat162_rn(float2{q2.x, q2.y});
            c1.h2[1] = __float22bfloat162_rn(float2{q2.z, q2.w});
            c1.h2[2] = __float22bfloat162_rn(float2{q3.x, q3.y});
            c1.h2[3] = __float22bfloat162_rn(float2{q3.z, q3.w});
        } else {
            c0.u = (u16x8)0;
            c1.u = (u16x8)0;
        }
        if (mt < 13) {
            f32x4 acc[5];
            #pragma unroll
            for (int nt = 0; nt < 5; ++nt)
                acc[nt] = (f32x4){0.f, 0.f, 0.f, 0.f};
            #pragma unroll
            for (int nt = 0; nt < 5; ++nt) {
                const int j = nt * 16 + lr;
                const bf16x8 b0 = *reinterpret_cast<const bf16x8*>(
                    &L.wefft[swz_gran(j, ks)]);
                const bf16x8 b1 = *reinterpret_cast<const bf16x8*>(
                    &L.wefft[swz_gran(j, 4 + ks)]);
                acc[nt] = __builtin_amdgcn_mfma_f32_16x16x32_bf16(
                    c0.bf, b0, acc[nt], 0, 0, 0);
                acc[nt] = __builtin_amdgcn_mfma_f32_16x16x32_bf16(
                    c1.bf, b1, acc[nt], 0, 0, 0);
            }
            #pragma unroll
            for (int r = 0; r < 4; ++r) {
                const int s = mt * 16 + ks * 4 + r;
                float p = 0.f;
                #pragma unroll
                for (int nt = 0; nt < 5; ++nt) {
                    const int j = nt * 16 + lr;
                    const float h = acc[nt][r] + L.bias_eff[j];
                    p += fmaxf(h, 0.f) * L.w2l[j];
                }
                p += __shfl_xor(p, 1);
                p += __shfl_xor(p, 2);
                p += __shfl_xor(p, 4);
                p += __shfl_xor(p, 8);
                if (lr == 0 && s < S_SZ) L.scores[s] = p;
            }
        }
    }
    __syncthreads();

    // ---- phase 4: softmax over 200 logits ----
    const float raw = (t < S_SZ) ? L.scores[t] : -1e30f;
    float m = raw;
    #pragma unroll
    for (int off = 32; off; off >>= 1) m = fmaxf(m, __shfl_xor(m, off));
    if ((t & 63) == 0) L.red[t >> 6] = m;
    __syncthreads();
    m = fmaxf(fmaxf(L.red[0], L.red[1]), fmaxf(L.red[2], L.red[3]));
    const float e = (t < S_SZ) ? __expf(raw - m) : 0.f;
    if (t < S_SZ) L.scores[t] = e;
    float ssum = e;
    #pragma unroll
    for (int off = 32; off; off >>= 1) ssum += __shfl_xor(ssum, off);
    if ((t & 63) == 0) L.red[4 + (t >> 6)] = ssum;
    __syncthreads();
    const float inv = 1.f / (L.red[4] + L.red[5] + L.red[6] + L.red[7]);

    // ---- phase 5: pooled — re-read rows from global (L3-hot), f32 ----
    // thread (wv,lr,ks) owns d = 8ks..8ks+7 and 32+8ks..32+8ks+7 of its rows
    {
        float pl[8], ph[8];
        #pragma unroll
        for (int e = 0; e < 8; ++e) { pl[e] = 0.f; ph[e] = 0.f; }
        #pragma unroll
        for (int i = 0; i < 4; ++i) {
            const int mt = wv + i * 4;
            const int r_ = rows_[i];
            if (r_ >= 0) {
                const int srow = mt * 16 + lr;
                const float w = L.scores[srow];
                const float4* src = reinterpret_cast<const float4*>(
                    item_table + (size_t)r_ * D_SZ);
                const float4 q0 = src[2 * ks];
                const float4 q1 = src[2 * ks + 1];
                const float4 q2 = src[8 + 2 * ks];
                const float4 q3 = src[8 + 2 * ks + 1];
                pl[0] = fmaf(w, q0.x, pl[0]); pl[1] = fmaf(w, q0.y, pl[1]);
                pl[2] = fmaf(w, q0.z, pl[2]); pl[3] = fmaf(w, q0.w, pl[3]);
                pl[4] = fmaf(w, q1.x, pl[4]); pl[5] = fmaf(w, q1.y, pl[5]);
                pl[6] = fmaf(w, q1.z, pl[6]); pl[7] = fmaf(w, q1.w, pl[7]);
                ph[0] = fmaf(w, q2.x, ph[0]); ph[1] = fmaf(w, q2.y, ph[1]);
                ph[2] = fmaf(w, q2.z, ph[2]); ph[3] = fmaf(w, q2.w, ph[3]);
                ph[4] = fmaf(w, q3.x, ph[4]); ph[5] = fmaf(w, q3.y, ph[5]);
                ph[6] = fmaf(w, q3.z, ph[6]); ph[7] = fmaf(w, q3.w, ph[7]);
            }
        }
        #pragma unroll
        for (int msk = 1; msk < 16; msk <<= 1) {
            #pragma unroll
            for (int e = 0; e < 8; ++e) {
                pl[e] += __shfl_xor(pl[e], msk);
                ph[e] += __shfl_xor(ph[e], msk);
            }
        }
        if (lr == 0) {
            #pragma unroll
            for (int e = 0; e < 8; ++e) {
                L.pp[wv * 64 + 8 * ks + e]      = pl[e];
                L.pp[wv * 64 + 32 + 8 * ks + e] = ph[e];
            }
        }
    }
    __syncthreads();
    if (t < D_SZ) {
        L.x[D_SZ + t] = (L.pp[t] + L.pp[64 + t]
                       + L.pp[128 + t] + L.pp[192 + t]) * inv;
    }
    __syncthreads();

    // ---- phase 6: prediction MLP 128 -> 64 -> 32 -> 1 (all threads) ----
    {
        const int j  = t & 63;
        const int k0 = (t >> 6) * 32;
        float acc = 0.f;
        for (int k = k0; k < k0 + 32; ++k)
            acc = fmaf(L.x[k], pred_w1[k * 64 + j], acc);
        L.pp[(t >> 6) * 64 + j] = acc;
    }
    __syncthreads();
    if (t < 64) {
        const float a = pred_b1[t] + L.pp[t] + L.pp[64 + t]
                      + L.pp[128 + t] + L.pp[192 + t];
        L.h1[t] = fmaxf(a, 0.f);
    }
    __syncthreads();
    {
        const int j  = t & 31;
        const int k0 = (t >> 5) * 8;
        float acc = 0.f;
        #pragma unroll
        for (int k = k0; k < k0 + 8; ++k)
            acc = fmaf(L.h1[k], pred_w2[k * 32 + j], acc);
        L.pp[(t >> 5) * 32 + j] = acc;
    }
    __syncthreads();
    if (t < 32) {
        float a = pred_b2[t];
        #pragma unroll
        for (int q = 0; q < 8; ++q) a += L.pp[q * 32 + t];
        float p = fmaxf(a, 0.f) * pred_w3[t];
        p += __shfl_xor(p, 1);
        p += __shfl_xor(p, 2);
        p += __shfl_xor(p, 4);
        p += __shfl_xor(p, 8);
        p += __shfl_xor(p, 16);
        if (t == 0) {
            const float z = p + pred_b3[0];
            out[b] = 1.f / (1.f + __expf(-z));
        }
    }
}

extern "C" void kernel_launch(void* const* d_in, const int* in_sizes, int n_in,
                              void* d_out, int out_size, void* d_ws, size_t ws_size,
                              hipStream_t stream)
{
    const int*   user_ids   = (const int*)  d_in[0];
    const int*   item_ids   = (const int*)  d_in[1];
    const int*   seq        = (const int*)  d_in[2];
    const float* user_table = (const float*)d_in[3];
    const float* item_table = (const float*)d_in[4];
    const float* att_w1     = (const float*)d_in[5];
    const float* att_b1     = (const float*)d_in[6];
    const float* att_w2     = (const float*)d_in[7];
    // d_in[8] = att_b2: cancels in softmax, unused
    const float* pred_w1    = (const float*)d_in[9];
    const float* pred_b1    = (const float*)d_in[10];
    const float* pred_w2    = (const float*)d_in[11];
    const float* pred_b2    = (const float*)d_in[12];
    const float* pred_w3    = (const float*)d_in[13];
    const float* pred_b3    = (const float*)d_in[14];
    float* out = (float*)d_out;

    din_fused<<<B_SZ, 256, 0, stream>>>(user_ids, item_ids, seq,
                                        user_table, item_table,
                                        att_w1, att_b1, att_w2,
                                        pred_w1, pred_b1, pred_w2, pred_b2,
                                        pred_w3, pred_b3, out);
}

// Round 8
// 90.113 us; speedup vs baseline: 1.8160x; 1.1201x over previous
//
#include <hip/hip_runtime.h>
#include <hip/hip_bf16.h>

// SimpleDIN fused kernel v8 — v5 structure done right: A-frags in REGISTERS
// across phases (fully static unrolls, no `break` -> no localMem), pool from
// registers, 13.8 KB LDS, launch_bounds(256,5).
//
// Algebra: feats=[beh,tgt,beh*tgt,beh-tgt] (K=256) collapses:
//   feats @ W1 == beh @ W_eff + bias_eff   (K=64)
//   W_eff[d,j]  = W1[d,j] + tgt[d]*W1[128+d,j] + W1[192+d,j]
//   bias_eff[j] = b1[j] + sum_d tgt[d]*(W1[64+d,j] - W1[192+d,j])
// att_b2 cancels in softmax.

#define B_SZ  4096
#define S_SZ  200
#define D_SZ  64
#define H_SZ  80

typedef __attribute__((ext_vector_type(8))) short          bf16x8;
typedef __attribute__((ext_vector_type(8))) unsigned short u16x8;
typedef __attribute__((ext_vector_type(4))) float          f32x4;

struct __align__(16) Lds {
    unsigned short wefft[H_SZ * 64];   // 10240 B, swizzled bf16 [j][d]
    float w2l[H_SZ];
    float bias_eff[H_SZ];
    float scores[S_SZ];
    float x[2 * D_SZ];
    float h1[64];
    float pp[4 * 64];
    float red[8];
};                                      // ~13.8 KB

__device__ __forceinline__ int swz_gran(int row, int g) {
    return row * 64 + ((g ^ (row & 7)) << 3);      // u16 index of 16B granule
}
__device__ __forceinline__ int swz_elem(int row, int col) {
    return row * 64 + (((col >> 3) ^ (row & 7)) << 3) + (col & 7);
}
__device__ __forceinline__ float bits2f(unsigned int u) {
    union { unsigned int u; float f; } v; v.u = u; return v.f;
}
__device__ __forceinline__ float bfelem(bf16x8 v, int e) {
    return bits2f(((unsigned int)(unsigned short)v[e]) << 16);
}

extern "C" __global__ __launch_bounds__(256, 5)
void din_fused(const int* __restrict__ user_ids,
               const int* __restrict__ item_ids,
               const int* __restrict__ seq,
               const float* __restrict__ user_table,
               const float* __restrict__ item_table,
               const float* __restrict__ att_w1,
               const float* __restrict__ att_b1,
               const float* __restrict__ att_w2,
               const float* __restrict__ pred_w1,
               const float* __restrict__ pred_b1,
               const float* __restrict__ pred_w2,
               const float* __restrict__ pred_b2,
               const float* __restrict__ pred_w3,
               const float* __restrict__ pred_b3,
               float* __restrict__ out)
{
    __shared__ Lds L;
    const int b = blockIdx.x;
    const int t = threadIdx.x;

    const int wv = t >> 6;                  // wave 0..3
    const int l  = t & 63;
    const int lr = l & 15;                  // M-row / N-col within tile
    const int ks = l >> 4;                  // k-slot 0..3

    // ---- phase 0: small per-block loads ----
    const int uid = user_ids[b];
    const int iid = item_ids[b];
    if (t < 64) {
        L.x[t] = user_table[(size_t)uid * D_SZ + t];
    } else if (t < 64 + H_SZ) {
        L.w2l[t - 64] = att_w2[t - 64];
    }

    // ---- phase 1: gather A-frags global -> registers -> bf16 ----
    // FULLY STATIC unroll (no break): A0/A1 indices compile-time constant.
    bf16x8 A0[4], A1[4];
    int rows_[4];
    #pragma unroll
    for (int i = 0; i < 4; ++i) {
        const int mt = wv + i * 4;
        const int srow = mt * 16 + lr;
        rows_[i] = (mt < 13 && srow < S_SZ) ? seq[b * S_SZ + srow] : -1;
    }
    #pragma unroll
    for (int i = 0; i < 4; ++i) {
        union { u16x8 u; bf16x8 bf; __hip_bfloat162 h2[4]; } c0, c1;
        if (rows_[i] >= 0) {
            const float4* src = reinterpret_cast<const float4*>(
                item_table + (size_t)rows_[i] * D_SZ);
            const float4 q0 = src[2 * ks];
            const float4 q1 = src[2 * ks + 1];
            const float4 q2 = src[8 + 2 * ks];
            const float4 q3 = src[8 + 2 * ks + 1];
            c0.h2[0] = __float22bfloat162_rn(float2{q0.x, q0.y});
            c0.h2[1] = __float22bfloat162_rn(float2{q0.z, q0.w});
            c0.h2[2] = __float22bfloat162_rn(float2{q1.x, q1.y});
            c0.h2[3] = __float22bfloat162_rn(float2{q1.z, q1.w});
            c1.h2[0] = __float22bfloat162_rn(float2{q2.x, q2.y});
            c1.h2[1] = __float22bfloat162_rn(float2{q2.z, q2.w});
            c1.h2[2] = __float22bfloat162_rn(float2{q3.x, q3.y});
            c1.h2[3] = __float22bfloat162_rn(float2{q3.z, q3.w});
        } else {
            c0.u = (u16x8)0;
            c1.u = (u16x8)0;
        }
        A0[i] = c0.bf;
        A1[i] = c1.bf;
    }

    // ---- phase 2: W_eff^T (bf16, swizzled) + bias_eff ----
    const float* tgtp = item_table + (size_t)iid * D_SZ;
    for (int i = t; i < 32 * H_SZ; i += 256) {
        const int dp = i / H_SZ;
        const int j  = i - dp * H_SZ;
        const int d  = dp * 2;
        const float2 tg = *reinterpret_cast<const float2*>(tgtp + d);
        const float w0 = att_w1[d * H_SZ + j]
                       + tg.x * att_w1[(128 + d) * H_SZ + j]
                       + att_w1[(192 + d) * H_SZ + j];
        const float w1 = att_w1[(d + 1) * H_SZ + j]
                       + tg.y * att_w1[(129 + d) * H_SZ + j]
                       + att_w1[(193 + d) * H_SZ + j];
        const __hip_bfloat162 hp = __float22bfloat162_rn(float2{w0, w1});
        *reinterpret_cast<__hip_bfloat162*>(&L.wefft[swz_elem(j, d)]) = hp;
    }
    if (t < 2 * H_SZ) {                     // 2 threads per j, 32 d each
        const int j = t >> 1;
        const int h = t & 1;
        float acc = h ? 0.f : att_b1[j];
        const int d0 = h * 32;
        #pragma unroll 4
        for (int d = d0; d < d0 + 32; ++d)
            acc += tgtp[d] * (att_w1[(64 + d) * H_SZ + j]
                            - att_w1[(192 + d) * H_SZ + j]);
        acc += __shfl_xor(acc, 1);
        if (h == 0) L.bias_eff[j] = acc;
    }
    __syncthreads();    // wefft + bias + w2l + x(user) ready

    // ---- phase 3: MFMA  C[s,j] = beh @ W_eff; logits = relu(C+b)·w2 ----
    #pragma unroll
    for (int i = 0; i < 4; ++i) {
        const int mt = wv + i * 4;
        if (mt < 13) {
            f32x4 acc[5];
            #pragma unroll
            for (int nt = 0; nt < 5; ++nt)
                acc[nt] = (f32x4){0.f, 0.f, 0.f, 0.f};
            #pragma unroll
            for (int nt = 0; nt < 5; ++nt) {
                const int j = nt * 16 + lr;
                const bf16x8 b0 = *reinterpret_cast<const bf16x8*>(
                    &L.wefft[swz_gran(j, ks)]);
                const bf16x8 b1 = *reinterpret_cast<const bf16x8*>(
                    &L.wefft[swz_gran(j, 4 + ks)]);
                acc[nt] = __builtin_amdgcn_mfma_f32_16x16x32_bf16(
                    A0[i], b0, acc[nt], 0, 0, 0);
                acc[nt] = __builtin_amdgcn_mfma_f32_16x16x32_bf16(
                    A1[i], b1, acc[nt], 0, 0, 0);
            }
            #pragma unroll
            for (int r = 0; r < 4; ++r) {
                const int s = mt * 16 + ks * 4 + r;
                float p = 0.f;
                #pragma unroll
                for (int nt = 0; nt < 5; ++nt) {
                    const int j = nt * 16 + lr;
                    const float h = acc[nt][r] + L.bias_eff[j];
                    p += fmaxf(h, 0.f) * L.w2l[j];
                }
                p += __shfl_xor(p, 1);
                p += __shfl_xor(p, 2);
                p += __shfl_xor(p, 4);
                p += __shfl_xor(p, 8);
                if (lr == 0 && s < S_SZ) L.scores[s] = p;
            }
        }
    }
    __syncthreads();

    // ---- phase 4: softmax over 200 logits ----
    const float raw = (t < S_SZ) ? L.scores[t] : -1e30f;
    float m = raw;
    #pragma unroll
    for (int off = 32; off; off >>= 1) m = fmaxf(m, __shfl_xor(m, off));
    if ((t & 63) == 0) L.red[t >> 6] = m;
    __syncthreads();
    m = fmaxf(fmaxf(L.red[0], L.red[1]), fmaxf(L.red[2], L.red[3]));
    const float e = (t < S_SZ) ? __expf(raw - m) : 0.f;
    if (t < S_SZ) L.scores[t] = e;
    float ssum = e;
    #pragma unroll
    for (int off = 32; off; off >>= 1) ssum += __shfl_xor(ssum, off);
    if ((t & 63) == 0) L.red[4 + (t >> 6)] = ssum;
    __syncthreads();
    const float inv = 1.f / (L.red[4] + L.red[5] + L.red[6] + L.red[7]);

    // ---- phase 5: pooled from A-frag registers (static indices) ----
    {
        float pl[8], ph[8];
        #pragma unroll
        for (int e = 0; e < 8; ++e) { pl[e] = 0.f; ph[e] = 0.f; }
        #pragma unroll
        for (int i = 0; i < 4; ++i) {
            const int mt = wv + i * 4;
            const int srow = mt * 16 + lr;
            const float w = (rows_[i] >= 0) ? L.scores[srow] : 0.f;
            #pragma unroll
            for (int e = 0; e < 8; ++e) {
                pl[e] = fmaf(w, bfelem(A0[i], e), pl[e]);
                ph[e] = fmaf(w, bfelem(A1[i], e), ph[e]);
            }
        }
        #pragma unroll
        for (int msk = 1; msk < 16; msk <<= 1) {
            #pragma unroll
            for (int e = 0; e < 8; ++e) {
                pl[e] += __shfl_xor(pl[e], msk);
                ph[e] += __shfl_xor(ph[e], msk);
            }
        }
        if (lr == 0) {
            #pragma unroll
            for (int e = 0; e < 8; ++e) {
                L.pp[wv * 64 + 8 * ks + e]      = pl[e];
                L.pp[wv * 64 + 32 + 8 * ks + e] = ph[e];
            }
        }
    }
    __syncthreads();
    if (t < D_SZ) {
        L.x[D_SZ + t] = (L.pp[t] + L.pp[64 + t]
                       + L.pp[128 + t] + L.pp[192 + t]) * inv;
    }
    __syncthreads();

    // ---- phase 6: prediction MLP 128 -> 64 -> 32 -> 1 (all threads) ----
    {
        const int j  = t & 63;
        const int k0 = (t >> 6) * 32;
        float acc = 0.f;
        for (int k = k0; k < k0 + 32; ++k)
            acc = fmaf(L.x[k], pred_w1[k * 64 + j], acc);
        L.pp[(t >> 6) * 64 + j] = acc;
    }
    __syncthreads();
    if (t < 64) {
        const float a = pred_b1[t] + L.pp[t] + L.pp[64 + t]
                      + L.pp[128 + t] + L.pp[192 + t];
        L.h1[t] = fmaxf(a, 0.f);
    }
    __syncthreads();
    {
        const int j  = t & 31;
        const int k0 = (t >> 5) * 8;
        float acc = 0.f;
        #pragma unroll
        for (int k = k0; k < k0 + 8; ++k)
            acc = fmaf(L.h1[k], pred_w2[k * 32 + j], acc);
        L.pp[(t >> 5) * 32 + j] = acc;
    }
    __syncthreads();
    if (t < 32) {
        float a = pred_b2[t];
        #pragma unroll
        for (int q = 0; q < 8; ++q) a += L.pp[q * 32 + t];
        float p = fmaxf(a, 0.f) * pred_w3[t];
        p += __shfl_xor(p, 1);
        p += __shfl_xor(p, 2);
        p += __shfl_xor(p, 4);
        p += __shfl_xor(p, 8);
        p += __shfl_xor(p, 16);
        if (t == 0) {
            const float z = p + pred_b3[0];
            out[b] = 1.f / (1.f + __expf(-z));
        }
    }
}

extern "C" void kernel_launch(void* const* d_in, const int* in_sizes, int n_in,
                              void* d_out, int out_size, void* d_ws, size_t ws_size,
                              hipStream_t stream)
{
    const int*   user_ids   = (const int*)  d_in[0];
    const int*   item_ids   = (const int*)  d_in[1];
    const int*   seq        = (const int*)  d_in[2];
    const float* user_table = (const float*)d_in[3];
    const float* item_table = (const float*)d_in[4];
    const float* att_w1     = (const float*)d_in[5];
    const float* att_b1     = (const float*)d_in[6];
    const float* att_w2     = (const float*)d_in[7];
    // d_in[8] = att_b2: cancels in softmax, unused
    const float* pred_w1    = (const float*)d_in[9];
    const float* pred_b1    = (const float*)d_in[10];
    const float* pred_w2    = (const float*)d_in[11];
    const float* pred_b2    = (const float*)d_in[12];
    const float* pred_w3    = (const float*)d_in[13];
    const float* pred_b3    = (const float*)d_in[14];
    float* out = (float*)d_out;

    din_fused<<<B_SZ, 256, 0, stream>>>(user_ids, item_ids, seq,
                                        user_table, item_table,
                                        att_w1, att_b1, att_w2,
                                        pred_w1, pred_b1, pred_w2, pred_b2,
                                        pred_w3, pred_b3, out);
}